// Round 7
// baseline (292.561 us; speedup 1.0000x reference)
//
#include <hip/hip_runtime.h>

// Problem constants (B=2, S=4096, D=512, H=8, Dh=64). f32 I/O, bf16 MFMA inside.
#define MTOT 8192  // B*S

typedef __attribute__((ext_vector_type(8))) short bf16x8;
typedef __attribute__((ext_vector_type(4))) float f32x4;

#if __has_builtin(__builtin_amdgcn_exp2f)
#define EXP2F __builtin_amdgcn_exp2f
#else
#define EXP2F exp2f
#endif

#define SC 0.18033688011112042f  // (1/8) * log2(e), folded into K
#define LDP 72                   // P/K LDS row stride (el): 36 dw == 4 mod 32
#define CTS 136                  // gemm C-tile stride (el): 68 dw == 4 mod 32

// RNE f32->bf16 (cold paths).
static __device__ __forceinline__ unsigned short f2b(float f) {
  union { float f; unsigned int i; } x;
  x.f = f;
  unsigned int i = x.i;
  return (unsigned short)((i + 0x7FFFu + ((i >> 16) & 1u)) >> 16);
}
// Truncation-pack two f32 -> bf16 pair (accuracy budget ample: 0.031 vs 0.099).
static __device__ __forceinline__ unsigned int pkt(float a, float b) {
  union { float f; unsigned int i; } xa, xb;
  xa.f = a; xb.f = b;
  return (xa.i >> 16) | (xb.i & 0xFFFF0000u);
}
static __device__ __forceinline__ bf16x8 ld8f32_bf16(const float* __restrict__ p) {
  f32x4 lo = *(const f32x4*)p;
  f32x4 hi = *(const f32x4*)(p + 4);
  union { unsigned int u[4]; bf16x8 v; } r;
  r.u[0] = pkt(lo[0], lo[1]);
  r.u[1] = pkt(lo[2], lo[3]);
  r.u[2] = pkt(hi[0], hi[1]);
  r.u[3] = pkt(hi[2], hi[3]);
  return r.v;
}

// ---------------------------------------------------------------------------
// Kernel 1: Q/V projection GEMM.  C[8192][1024] = mf @ Wc^T + bc.
//   Q sector (cols 0..511):  Q_ws[bh][s][dh]   (row-major, dh contig)
//   V sector (cols 512..1023): Vt_ws[bh][dh][s] (TRANSPOSED, s contig)
// Epilogue round-trips through a padded LDS tile for fully coalesced b128
// global stores (R6's 2-byte scatter was ~60us of the kernel).
// ---------------------------------------------------------------------------
__global__ __launch_bounds__(256) void gemm_qv(
    const float* __restrict__ mf,
    const float* __restrict__ Wc,
    const float* __restrict__ bc,
    unsigned short* __restrict__ qvws)
{
  const int bid = blockIdx.x;
  const int tn = bid & 7, tm = bid >> 3;    // 8 col tiles (0-3 Q, 4-7 V), 64 row tiles
  const int w = threadIdx.x >> 6, lane = threadIdx.x & 63;
  const int n = lane & 15, q = lane >> 4;
  const int row0 = tm * 128 + (w >> 1) * 64;
  const int col0 = tn * 128 + (w & 1) * 64;

  f32x4 acc[4][4] = {};

  for (int kk = 0; kk < 512; kk += 32) {
    bf16x8 a[4], b[4];
#pragma unroll
    for (int si = 0; si < 4; ++si)
      a[si] = ld8f32_bf16(mf + (size_t)(row0 + si * 16 + n) * 512 + kk + q * 8);
#pragma unroll
    for (int sj = 0; sj < 4; ++sj) {
      const int nb = col0 + sj * 16 + n;
      b[sj] = ld8f32_bf16(Wc + (size_t)nb * 512 + kk + q * 8);
    }
#pragma unroll
    for (int si = 0; si < 4; ++si)
#pragma unroll
      for (int sj = 0; sj < 4; ++sj)
        acc[si][sj] = __builtin_amdgcn_mfma_f32_16x16x32_bf16(a[si], b[sj], acc[si][sj], 0, 0, 0);
  }

  __shared__ alignas(16) unsigned short Ct[128 * CTS];
  const bool isV = (tn >= 4);
  const int rl0 = (w >> 1) * 64;  // wave's local row base (s-direction)
  const int cl0 = (w & 1) * 64;   // wave's local col base (nb-direction)

  if (!isV) {
    // Q: Ct[s_local][nb_local] (transpose from C-layout via b16 writes)
#pragma unroll
    for (int sj = 0; sj < 4; ++sj) {
      const float bias = bc[col0 + sj * 16 + n];
#pragma unroll
      for (int si = 0; si < 4; ++si)
#pragma unroll
        for (int r = 0; r < 4; ++r)
          Ct[(rl0 + si * 16 + q * 4 + r) * CTS + cl0 + sj * 16 + n] =
              f2b(acc[si][sj][r] + bias);
    }
  } else {
    // V: Ct[nb_local][s_local] -- C regs already s-consecutive -> packed b64
#pragma unroll
    for (int sj = 0; sj < 4; ++sj) {
      const float bias = bc[col0 + sj * 16 + n];
#pragma unroll
      for (int si = 0; si < 4; ++si) {
        uint2 pk;
        pk.x = pkt(acc[si][sj][0] + bias, acc[si][sj][1] + bias);
        pk.y = pkt(acc[si][sj][2] + bias, acc[si][sj][3] + bias);
        *(uint2*)(&Ct[(cl0 + sj * 16 + n) * CTS + rl0 + si * 16 + q * 4]) = pk;
      }
    }
  }
  __syncthreads();

  // Coalesced readout: 8 consecutive threads cover one 128B LDS row-run.
  const int rk = threadIdx.x & 7;
  const int rr = threadIdx.x >> 3;  // 0..31
#pragma unroll
  for (int rp = 0; rp < 4; ++rp) {
    const int row = rp * 32 + rr;
#pragma unroll
    for (int ch = 0; ch < 2; ++ch) {
      const int col = ch * 64 + rk * 8;
      bf16x8 v = *(const bf16x8*)(&Ct[row * CTS + col]);
      if (!isV) {
        const int srow = tm * 128 + row;
        const int bb = srow >> 12, ss = srow & 4095;
        const int nbg = tn * 128 + col;          // 0..511
        const int hh = nbg >> 6, dh0 = nbg & 63;
        *(bf16x8*)(qvws + ((size_t)((bb * 8 + hh) * 4096 + ss)) * 64 + dh0) = v;
      } else {
        const int nbv = tn * 128 + row - 512;    // 0..511
        const int hh = nbv >> 6, dh0 = nbv & 63;
        const int scol = tm * 128 + col;
        const int bb = scol >> 12, ss = scol & 4095;
        *(bf16x8*)(qvws + (size_t)MTOT * 512 +
                   ((size_t)((bb * 8 + hh) * 64 + dh0)) * 4096 + ss) = v;
      }
    }
  }
}

// ---------------------------------------------------------------------------
// Kernel 2: flash attention, global-frag edition.
//  - block = 2 waves, one (b,h) x 64 i-rows; wave handles HALF the j-range
//    (no-max softmax is associative -> exact partial merge at the end)
//  - bq (Q rows) and bvv (V^T rows) MFMA frags loaded DIRECTLY from global
//    (both 16B-contiguous thanks to ws layouts) -> LDS only holds P
//  - ZERO barriers inside the j-loop (P buffers are per-wave)
//  - K tile computed once per block (waves split rows), shared via LDS
// ---------------------------------------------------------------------------
__global__ __launch_bounds__(128, 2) void attn_kernel(
    const unsigned short* __restrict__ qvws,
    const float* __restrict__ mf,
    const float* __restrict__ Wv,
    const float* __restrict__ bv,
    float* __restrict__ out)
{
  const int bid = blockIdx.x;
  const int bh = bid >> 6;            // 16 (b,h)
  const int ib = bid & 63;            // 64 i-blocks of 64 rows
  const int b_ = bh >> 3, h = bh & 7;
  const int w = threadIdx.x >> 6, lane = threadIdx.x & 63;
  const int n = lane & 15, q = lane >> 4;
  const int i0 = ib * 64;

  __shared__ alignas(16) unsigned short PK[2][64 * LDP];  // per-wave P; PK[0] also K-tile & merge buf
  __shared__ float lbuf[64];

  const unsigned short* Qb = qvws + (size_t)(bh * 4096) * 64;
  const unsigned short* Vb = qvws + (size_t)MTOT * 512 + (size_t)(bh * 64) * 4096;

  // ---- K-init: wave w computes rows (2w+sl)*16, sl in {0,1} -> PK[0] ----
  {
    f32x4 ka[2][4] = {};
    for (int kk = 0; kk < 512; kk += 32) {
      bf16x8 a0 = ld8f32_bf16(mf + (size_t)(b_ * 4096 + i0 + (2 * w + 0) * 16 + n) * 512 + kk + q * 8);
      bf16x8 a1 = ld8f32_bf16(mf + (size_t)(b_ * 4096 + i0 + (2 * w + 1) * 16 + n) * 512 + kk + q * 8);
#pragma unroll
      for (int t = 0; t < 4; ++t) {
        bf16x8 bw = ld8f32_bf16(Wv + (size_t)(h * 64 + t * 16 + n) * 512 + kk + q * 8);
        ka[0][t] = __builtin_amdgcn_mfma_f32_16x16x32_bf16(a0, bw, ka[0][t], 0, 0, 0);
        ka[1][t] = __builtin_amdgcn_mfma_f32_16x16x32_bf16(a1, bw, ka[1][t], 0, 0, 0);
      }
    }
#pragma unroll
    for (int sl = 0; sl < 2; ++sl)
#pragma unroll
      for (int t = 0; t < 4; ++t) {
        const float bias = bv[h * 64 + t * 16 + n];
#pragma unroll
        for (int r = 0; r < 4; ++r)
          PK[0][((2 * w + sl) * 16 + q * 4 + r) * LDP + t * 16 + n] =
              f2b((ka[sl][t][r] + bias) * SC);
      }
  }
  __syncthreads();
  bf16x8 aK[4][2];
#pragma unroll
  for (int sub = 0; sub < 4; ++sub)
#pragma unroll
    for (int s = 0; s < 2; ++s)
      aK[sub][s] = *(const bf16x8*)(&PK[0][(sub * 16 + n) * LDP + s * 32 + q * 8]);
  __syncthreads();  // PK[0] now free for wave 0's P

  f32x4 o[4][4] = {};
  f32x4 lacc[4] = {};
  const bf16x8 ones = {(short)0x3F80, (short)0x3F80, (short)0x3F80, (short)0x3F80,
                       (short)0x3F80, (short)0x3F80, (short)0x3F80, (short)0x3F80};
  unsigned short* Pw = &PK[w][0];

  // ---- j-loop: 32 iters of 64 over this wave's half; NO barriers ----
  for (int it = 0; it < 32; ++it) {
    const int j0 = w * 2048 + it * 64;

    // Q frags straight from global (16B contiguous).
    bf16x8 bq[4][2];
#pragma unroll
    for (int jt = 0; jt < 4; ++jt)
#pragma unroll
      for (int s = 0; s < 2; ++s)
        bq[jt][s] = *(const bf16x8*)(Qb + (size_t)(j0 + jt * 16 + n) * 64 + s * 32 + q * 8);

    // Scores per i-sub (keeps c-register pressure at 4 f32x4):
    // c = Q . K^T transposed -> lane holds S[j=jt*16+q*4+r][i=sub*16+n]
#pragma unroll
    for (int sub = 0; sub < 4; ++sub) {
      f32x4 c[4] = {};
#pragma unroll
      for (int jt = 0; jt < 4; ++jt)
#pragma unroll
        for (int s = 0; s < 2; ++s)
          c[jt] = __builtin_amdgcn_mfma_f32_16x16x32_bf16(bq[jt][s], aK[sub][s], c[jt], 0, 0, 0);
#pragma unroll
      for (int jt = 0; jt < 4; ++jt) {
        uint2 pk;
        pk.x = pkt(EXP2F(c[jt][0]), EXP2F(c[jt][1]));
        pk.y = pkt(EXP2F(c[jt][2]), EXP2F(c[jt][3]));
        *(uint2*)(Pw + (sub * 16 + n) * LDP + jt * 16 + q * 4) = pk;
      }
    }
    asm volatile("s_waitcnt lgkmcnt(0)" ::: "memory");  // wave-local P drain

    // P.V + l, per k-half (V^T frags straight from global).
#pragma unroll
    for (int s = 0; s < 2; ++s) {
      bf16x8 bvv[4];
#pragma unroll
      for (int t = 0; t < 4; ++t)
        bvv[t] = *(const bf16x8*)(Vb + (size_t)(t * 16 + n) * 4096 + j0 + s * 32 + q * 8);
#pragma unroll
      for (int sub = 0; sub < 4; ++sub) {
        bf16x8 pa = *(const bf16x8*)(Pw + (sub * 16 + n) * LDP + s * 32 + q * 8);
        lacc[sub] = __builtin_amdgcn_mfma_f32_16x16x32_bf16(pa, ones, lacc[sub], 0, 0, 0);
#pragma unroll
        for (int t = 0; t < 4; ++t)
          o[sub][t] = __builtin_amdgcn_mfma_f32_16x16x32_bf16(pa, bvv[t], o[sub][t], 0, 0, 0);
      }
    }
  }

  // ---- merge the two j-halves (f32, exact) + epilogue ----
  __syncthreads();  // both waves done with their P regions
  float* mO = (float*)&PK[0][0];  // 64 x (stride 68) f32 = 17408 B <= 18432 B
  if (w == 1) {
#pragma unroll
    for (int sub = 0; sub < 4; ++sub) {
#pragma unroll
      for (int t = 0; t < 4; ++t)
#pragma unroll
        for (int r = 0; r < 4; ++r)
          mO[(sub * 16 + q * 4 + r) * 68 + t * 16 + n] = o[sub][t][r];
      if (n == 0)
#pragma unroll
        for (int r = 0; r < 4; ++r)
          lbuf[sub * 16 + q * 4 + r] = lacc[sub][r];
    }
  }
  __syncthreads();
  if (w == 0) {
#pragma unroll
    for (int sub = 0; sub < 4; ++sub) {
      float li[4];
#pragma unroll
      for (int r = 0; r < 4; ++r)
        li[r] = 1.0f / (lacc[sub][r] + lbuf[sub * 16 + q * 4 + r]);
#pragma unroll
      for (int t = 0; t < 4; ++t) {
#pragma unroll
        for (int r = 0; r < 4; ++r) {
          const int i = i0 + sub * 16 + q * 4 + r;
          const int dh = t * 16 + n;
          const size_t idx = (size_t)(b_ * 4096 + i) * 512 + h * 64 + dh;
          out[idx] = (o[sub][t][r] + mO[(sub * 16 + q * 4 + r) * 68 + t * 16 + n]) * li[r]
                     + mf[idx];
        }
      }
    }
  }
}

extern "C" void kernel_launch(void* const* d_in, const int* in_sizes, int n_in,
                              void* d_out, int out_size, void* d_ws, size_t ws_size,
                              hipStream_t stream) {
  const float* mf = (const float*)d_in[0];  // (2,4096,512) f32
  const float* Wc = (const float*)d_in[1];  // (1024,512) f32
  const float* bc = (const float*)d_in[2];  // (1024,) f32
  const float* Wv = (const float*)d_in[3];  // (512,512) f32
  const float* bv = (const float*)d_in[4];  // (512,) f32
  float* out = (float*)d_out;
  unsigned short* qvws = (unsigned short*)d_ws;  // Q + V^T bf16 = 16 MiB

  gemm_qv<<<512, 256, 0, stream>>>(mf, Wc, bc, qvws);
  // 16 (b,h) x 64 i-blocks of 64 rows; 2 waves/block (j-split halves)
  attn_kernel<<<1024, 128, 0, stream>>>(qvws, mf, Wv, bv, out);
}

// Round 8
// 248.307 us; speedup vs baseline: 1.1782x; 1.1782x over previous
//
#include <hip/hip_runtime.h>

// Problem constants (B=2, S=4096, D=512, H=8, Dh=64). f32 I/O, bf16 MFMA inside.
#define MTOT 8192  // B*S

typedef __attribute__((ext_vector_type(8))) short bf16x8;
typedef __attribute__((ext_vector_type(4))) float f32x4;

#if __has_builtin(__builtin_amdgcn_exp2f)
#define EXP2F __builtin_amdgcn_exp2f
#else
#define EXP2F exp2f
#endif

#define SC 0.18033688011112042f  // (1/8) * log2(e), folded into K
#define LDP 72                   // LDS row stride (el): 36 dw == 4 mod 32
#define CTS 136                  // epilogue C-tile stride (el)

// Truncation f32->bf16 (1 VALU). Error budget ample (0.031 vs 0.099 thresh).
static __device__ __forceinline__ unsigned short tb(float f) {
  union { float f; unsigned int i; } x;
  x.f = f;
  return (unsigned short)(x.i >> 16);
}
static __device__ __forceinline__ unsigned int pkt(float a, float b) {
  union { float f; unsigned int i; } xa, xb;
  xa.f = a; xb.f = b;
  return (xa.i >> 16) | (xb.i & 0xFFFF0000u);
}
static __device__ __forceinline__ bf16x8 ld8f32_bf16(const float* __restrict__ p) {
  f32x4 lo = *(const f32x4*)p;
  f32x4 hi = *(const f32x4*)(p + 4);
  union { unsigned int u[4]; bf16x8 v; } r;
  r.u[0] = pkt(lo[0], lo[1]);
  r.u[1] = pkt(lo[2], lo[3]);
  r.u[2] = pkt(hi[0], hi[1]);
  r.u[3] = pkt(hi[2], hi[3]);
  return r.v;
}

// ---------------------------------------------------------------------------
// Kernel 1: projection GEMM, LDS-staged (coalesced loads, convert-once).
// Columns: [0,512) Q (Wc,+bc) -> Q_ws[bh][s][dh]
//          [512,1024) V (Wc,+bc) -> Vt_ws[bh][dh][s] (transposed)
//          [1024,1536) K (Wv,+bv, *SC) -> K_ws[bh][s][dh]   (only if nct==12)
// ---------------------------------------------------------------------------
__global__ __launch_bounds__(256) void gemm_qvk(
    const float* __restrict__ mf,
    const float* __restrict__ Wc,
    const float* __restrict__ bc,
    const float* __restrict__ Wv,
    const float* __restrict__ bv,
    unsigned short* __restrict__ ws,
    int nct)
{
  const int bid = blockIdx.x;
  const int tn = bid % nct, tm = bid / nct;
  const int w = threadIdx.x >> 6, lane = threadIdx.x & 63;
  const int n = lane & 15, q = lane >> 4;

  __shared__ alignas(16) unsigned short smem[2 * 128 * LDP];  // As | Bs; Ct overlay
  unsigned short* As = smem;
  unsigned short* Bs = smem + 128 * LDP;

  f32x4 acc[4][4] = {};
  const int rowA0 = tm * 128, colB0 = tn * 128;
  const int sr = threadIdx.x >> 4;          // 0..15 row within round
  const int sc = (threadIdx.x & 15) * 4;    // f32 col offset (16B)

  for (int kc = 0; kc < 512; kc += 64) {
    __syncthreads();
#pragma unroll
    for (int rr = 0; rr < 8; ++rr) {
      const int row = rr * 16 + sr;
      f32x4 av = *(const f32x4*)(mf + (size_t)(rowA0 + row) * 512 + kc + sc);
      uint2 ap; ap.x = pkt(av[0], av[1]); ap.y = pkt(av[2], av[3]);
      *(uint2*)(&As[row * LDP + sc]) = ap;
      const int c = colB0 + row;
      const float* bsrc = (c < 1024) ? (Wc + (size_t)c * 512)
                                     : (Wv + (size_t)(c - 1024) * 512);
      f32x4 bvx = *(const f32x4*)(bsrc + kc + sc);
      uint2 bp; bp.x = pkt(bvx[0], bvx[1]); bp.y = pkt(bvx[2], bvx[3]);
      *(uint2*)(&Bs[row * LDP + sc]) = bp;
    }
    __syncthreads();
#pragma unroll
    for (int ks = 0; ks < 2; ++ks) {
      bf16x8 a[4], b[4];
#pragma unroll
      for (int si = 0; si < 4; ++si)
        a[si] = *(const bf16x8*)(&As[((w >> 1) * 64 + si * 16 + n) * LDP + ks * 32 + q * 8]);
#pragma unroll
      for (int sj = 0; sj < 4; ++sj)
        b[sj] = *(const bf16x8*)(&Bs[((w & 1) * 64 + sj * 16 + n) * LDP + ks * 32 + q * 8]);
#pragma unroll
      for (int si = 0; si < 4; ++si)
#pragma unroll
        for (int sj = 0; sj < 4; ++sj)
          acc[si][sj] = __builtin_amdgcn_mfma_f32_16x16x32_bf16(a[si], b[sj], acc[si][sj], 0, 0, 0);
    }
  }

  // ---- epilogue: LDS transpose (Ct overlays As/Bs) then coalesced stores ----
  __syncthreads();
  unsigned short* Ct = smem;                 // [128][CTS]
  const bool isV = (tn >= 4 && tn < 8);
  const int rl0 = (w >> 1) * 64, cl0 = (w & 1) * 64;

  if (!isV) {
    const bool isK = (tn >= 8);
#pragma unroll
    for (int sj = 0; sj < 4; ++sj) {
      const int c = colB0 + sj * 16 + n;
      const float bias = isK ? bv[c - 1024] : bc[c];
#pragma unroll
      for (int si = 0; si < 4; ++si)
#pragma unroll
        for (int r = 0; r < 4; ++r) {
          float v = acc[si][sj][r] + bias;
          if (isK) v *= SC;
          Ct[(rl0 + si * 16 + q * 4 + r) * CTS + cl0 + sj * 16 + n] = tb(v);
        }
    }
  } else {
#pragma unroll
    for (int sj = 0; sj < 4; ++sj) {
      const float bias = bc[colB0 + sj * 16 + n];
#pragma unroll
      for (int si = 0; si < 4; ++si) {
        uint2 pk;
        pk.x = pkt(acc[si][sj][0] + bias, acc[si][sj][1] + bias);
        pk.y = pkt(acc[si][sj][2] + bias, acc[si][sj][3] + bias);
        *(uint2*)(&Ct[(cl0 + sj * 16 + n) * CTS + rl0 + si * 16 + q * 4]) = pk;
      }
    }
  }
  __syncthreads();

  const int rk = threadIdx.x & 7, rr2 = threadIdx.x >> 3;
#pragma unroll
  for (int rp = 0; rp < 4; ++rp) {
    const int row = rp * 32 + rr2;
#pragma unroll
    for (int ch = 0; ch < 2; ++ch) {
      const int col = ch * 64 + rk * 8;
      bf16x8 v = *(const bf16x8*)(&Ct[row * CTS + col]);
      if (!isV) {
        const int srow = rowA0 + row;
        const int bb = srow >> 12, ss = srow & 4095;
        const int cg = colB0 + col;
        const int cl = (cg >= 1024) ? (cg - 1024) : cg;   // K maps to [0,512)
        const int hh = cl >> 6, dh0 = cl & 63;
        unsigned short* base = (cg >= 1024) ? (ws + (size_t)2 * MTOT * 512) : ws;
        *(bf16x8*)(base + ((size_t)((bb * 8 + hh) * 4096 + ss)) * 64 + dh0) = v;
      } else {
        const int cv = (tn - 4) * 128 + row;              // [0,512)
        const int hh = cv >> 6, dh0 = cv & 63;
        const int sg = rowA0 + col;
        const int bb = sg >> 12, ss = sg & 4095;
        *(bf16x8*)(ws + (size_t)MTOT * 512 +
                   ((size_t)((bb * 8 + hh) * 64 + dh0)) * 4096 + ss) = v;
      }
    }
  }
}

// ---------------------------------------------------------------------------
// Kernel 2: flash attention, software-pipelined, zero in-loop barriers.
//  - block = 2 waves, one (b,h) x 64 i-rows; waves split j (exact f32 merge)
//  - XCD swizzle: XCD x gets bh {2x,2x+1} -> Q/V/K working set L2-resident
//  - next-iter bq issued BEFORE the lgkm wait; bvv after PV (latency hidden)
//  - KWS: read precomputed K from ws; else compute K tile in-kernel (fallback)
// ---------------------------------------------------------------------------
template <bool KWS>
__global__ __launch_bounds__(128, 2) void attn_kernel(
    const unsigned short* __restrict__ qvws,
    const float* __restrict__ mf,
    const float* __restrict__ Wv,
    const float* __restrict__ bv,
    float* __restrict__ out)
{
  const int bid = blockIdx.x;
  const int bh = ((bid & 7) << 1) | ((bid >> 3) & 1);  // XCD-local bh pairing
  const int ib = bid >> 4;
  const int b_ = bh >> 3, h = bh & 7;
  const int w = threadIdx.x >> 6, lane = threadIdx.x & 63;
  const int n = lane & 15, q = lane >> 4;
  const int i0 = ib * 64;

  __shared__ alignas(16) unsigned short PK[2][64 * LDP];
  __shared__ float lbuf[64];

  const unsigned short* Qb = qvws + (size_t)(bh * 4096) * 64;
  const unsigned short* Vb = qvws + (size_t)MTOT * 512 + (size_t)(bh * 64) * 4096;

  bf16x8 aK[4][2];
  if (KWS) {
    const unsigned short* Kb = qvws + (size_t)2 * MTOT * 512 + (size_t)(bh * 4096) * 64;
#pragma unroll
    for (int sub = 0; sub < 4; ++sub)
#pragma unroll
      for (int s = 0; s < 2; ++s)
        aK[sub][s] = *(const bf16x8*)(Kb + (size_t)(i0 + sub * 16 + n) * 64 + s * 32 + q * 8);
  } else {
    // Fallback: compute K tile (64 rows) in-block; wave w does subs {2w,2w+1}.
    f32x4 ka[2][4] = {};
    for (int kk = 0; kk < 512; kk += 32) {
      bf16x8 a0 = ld8f32_bf16(mf + (size_t)(b_ * 4096 + i0 + (2 * w + 0) * 16 + n) * 512 + kk + q * 8);
      bf16x8 a1 = ld8f32_bf16(mf + (size_t)(b_ * 4096 + i0 + (2 * w + 1) * 16 + n) * 512 + kk + q * 8);
#pragma unroll
      for (int t = 0; t < 4; ++t) {
        bf16x8 bw = ld8f32_bf16(Wv + (size_t)(h * 64 + t * 16 + n) * 512 + kk + q * 8);
        ka[0][t] = __builtin_amdgcn_mfma_f32_16x16x32_bf16(a0, bw, ka[0][t], 0, 0, 0);
        ka[1][t] = __builtin_amdgcn_mfma_f32_16x16x32_bf16(a1, bw, ka[1][t], 0, 0, 0);
      }
    }
#pragma unroll
    for (int sl = 0; sl < 2; ++sl)
#pragma unroll
      for (int t = 0; t < 4; ++t) {
        const float bias = bv[h * 64 + t * 16 + n];
#pragma unroll
        for (int r = 0; r < 4; ++r)
          PK[0][((2 * w + sl) * 16 + q * 4 + r) * LDP + t * 16 + n] =
              tb((ka[sl][t][r] + bias) * SC);
      }
    __syncthreads();
#pragma unroll
    for (int sub = 0; sub < 4; ++sub)
#pragma unroll
      for (int s = 0; s < 2; ++s)
        aK[sub][s] = *(const bf16x8*)(&PK[0][(sub * 16 + n) * LDP + s * 32 + q * 8]);
    __syncthreads();
  }

  f32x4 o[4][4] = {};
  f32x4 lacc[4] = {};
  const bf16x8 ones = {(short)0x3F80, (short)0x3F80, (short)0x3F80, (short)0x3F80,
                       (short)0x3F80, (short)0x3F80, (short)0x3F80, (short)0x3F80};
  unsigned short* Pw = &PK[w][0];
  const int jbase = w * 2048;

  // Prefetch iteration 0.
  bf16x8 bq[4][2], bvv[4][2];
#pragma unroll
  for (int jt = 0; jt < 4; ++jt)
#pragma unroll
    for (int s = 0; s < 2; ++s)
      bq[jt][s] = *(const bf16x8*)(Qb + (size_t)(jbase + jt * 16 + n) * 64 + s * 32 + q * 8);
#pragma unroll
  for (int t = 0; t < 4; ++t)
#pragma unroll
    for (int s = 0; s < 2; ++s)
      bvv[t][s] = *(const bf16x8*)(Vb + (size_t)(t * 16 + n) * 4096 + jbase + s * 32 + q * 8);

  for (int it = 0; it < 32; ++it) {
    const int j1 = jbase + ((it + 1) & 31) * 64;  // next tile (wraps; redundant last)

    // Scores (transposed: lane holds S[j][i=sub*16+n]); P to per-wave LDS.
#pragma unroll
    for (int sub = 0; sub < 4; ++sub) {
      f32x4 c[4] = {};
#pragma unroll
      for (int jt = 0; jt < 4; ++jt)
#pragma unroll
        for (int s = 0; s < 2; ++s)
          c[jt] = __builtin_amdgcn_mfma_f32_16x16x32_bf16(bq[jt][s], aK[sub][s], c[jt], 0, 0, 0);
#pragma unroll
      for (int jt = 0; jt < 4; ++jt) {
        uint2 pk;
        pk.x = pkt(EXP2F(c[jt][0]), EXP2F(c[jt][1]));
        pk.y = pkt(EXP2F(c[jt][2]), EXP2F(c[jt][3]));
        *(uint2*)(Pw + (sub * 16 + n) * LDP + jt * 16 + q * 4) = pk;
      }
    }

    // Issue next bq NOW (bq regs dead) -- hides L2 latency behind PV + wait.
#pragma unroll
    for (int jt = 0; jt < 4; ++jt)
#pragma unroll
      for (int s = 0; s < 2; ++s)
        bq[jt][s] = *(const bf16x8*)(Qb + (size_t)(j1 + jt * 16 + n) * 64 + s * 32 + q * 8);

    asm volatile("s_waitcnt lgkmcnt(0)" ::: "memory");  // wave-local P drain

    // P.V + l (40 MFMAs).
#pragma unroll
    for (int s = 0; s < 2; ++s) {
#pragma unroll
      for (int sub = 0; sub < 4; ++sub) {
        bf16x8 pa = *(const bf16x8*)(Pw + (sub * 16 + n) * LDP + s * 32 + q * 8);
        lacc[sub] = __builtin_amdgcn_mfma_f32_16x16x32_bf16(pa, ones, lacc[sub], 0, 0, 0);
#pragma unroll
        for (int t = 0; t < 4; ++t)
          o[sub][t] = __builtin_amdgcn_mfma_f32_16x16x32_bf16(pa, bvv[t][s], o[sub][t], 0, 0, 0);
      }
    }

    // Issue next bvv (bvv regs dead).
#pragma unroll
    for (int t = 0; t < 4; ++t)
#pragma unroll
      for (int s = 0; s < 2; ++s)
        bvv[t][s] = *(const bf16x8*)(Vb + (size_t)(t * 16 + n) * 4096 + j1 + s * 32 + q * 8);
  }

  // ---- split merge: wave w exports subs it does NOT keep; each stores half ----
  __syncthreads();                    // both waves done with P regions
  float* mO = (float*)&PK[0][0];      // 64 x (stride 68) f32, overlays P
  const int ebase = (w == 0) ? 0 : 32;      // where I write
  const int rbase = (w == 0) ? 32 : 0;      // where I read
  const int esub0 = (w == 0) ? 2 : 0;       // subs I export
  const int ksub0 = (w == 0) ? 0 : 2;       // subs I keep
#pragma unroll
  for (int sl = 0; sl < 2; ++sl) {
    const int sub = esub0 + sl;
#pragma unroll
    for (int t = 0; t < 4; ++t)
#pragma unroll
      for (int r = 0; r < 4; ++r)
        mO[(ebase + sl * 16 + q * 4 + r) * 68 + t * 16 + n] = o[sub][t][r];
    if (n == 0)
#pragma unroll
      for (int r = 0; r < 4; ++r)
        lbuf[ebase + sl * 16 + q * 4 + r] = lacc[sub][r];
  }
  __syncthreads();
#pragma unroll
  for (int sl = 0; sl < 2; ++sl) {
    const int sub = ksub0 + sl;
    float li[4];
#pragma unroll
    for (int r = 0; r < 4; ++r)
      li[r] = 1.0f / (lacc[sub][r] + lbuf[rbase + sl * 16 + q * 4 + r]);
#pragma unroll
    for (int t = 0; t < 4; ++t) {
#pragma unroll
      for (int r = 0; r < 4; ++r) {
        const int i = i0 + sub * 16 + q * 4 + r;
        const int dh = t * 16 + n;
        const size_t idx = (size_t)(b_ * 4096 + i) * 512 + h * 64 + dh;
        out[idx] = (o[sub][t][r] + mO[(rbase + sl * 16 + q * 4 + r) * 68 + t * 16 + n]) * li[r]
                   + mf[idx];
      }
    }
  }
}

extern "C" void kernel_launch(void* const* d_in, const int* in_sizes, int n_in,
                              void* d_out, int out_size, void* d_ws, size_t ws_size,
                              hipStream_t stream) {
  const float* mf = (const float*)d_in[0];  // (2,4096,512) f32
  const float* Wc = (const float*)d_in[1];  // (1024,512) f32
  const float* bc = (const float*)d_in[2];  // (1024,) f32
  const float* Wv = (const float*)d_in[3];  // (512,512) f32
  const float* bv = (const float*)d_in[4];  // (512,) f32
  float* out = (float*)d_out;
  unsigned short* ws = (unsigned short*)d_ws;

  // Fast path needs Q(8MB) + V^T(8MB) + K(8MB) in ws.
  const bool kws = ws_size >= (size_t)3 * MTOT * 512 * 2;
  const int nct = kws ? 12 : 8;

  gemm_qvk<<<64 * nct, 256, 0, stream>>>(mf, Wc, bc, Wv, bv, ws, nct);
  if (kws)
    attn_kernel<true><<<1024, 128, 0, stream>>>(ws, mf, Wv, bv, out);
  else
    attn_kernel<false><<<1024, 128, 0, stream>>>(ws, mf, Wv, bv, out);
}